// Round 9
// baseline (182.677 us; speedup 1.0000x reference)
//
#include <hip/hip_runtime.h>

#define M_ANT 64
#define POWER_CONSTR 1.0f

typedef float f32x4 __attribute__((ext_vector_type(4)));

// ---------------------------------------------------------------------------
// Kernel 1: per-block partial energies per antenna — block-CONTIGUOUS chunks.
// Block b owns float4s [b*chunk, (b+1)*chunk); thread steps by 256 float4s.
// chunk is a multiple of 256, so (base>>2) % 64 == 0 and each thread's
// antenna stays FIXED: antenna = (tid>>2)&63. Per-block access is purely
// sequential 4KB bursts -> max DRAM row locality (vs 8MB-strided hops).
// NT loads (zero reuse). Fixed-order LDS combine (deterministic).
// ---------------------------------------------------------------------------
__global__ __launch_bounds__(256) void energy_partial(
    const f32x4* __restrict__ P4, float* __restrict__ partials, int nvec,
    int chunk) {
  const int tid = threadIdx.x;
  const int base = blockIdx.x * chunk;
  int end = base + chunk;
  if (end > nvec) end = nvec;

  float acc = 0.0f;
  int f = base + tid;
  for (; f + 768 < end; f += 1024) {  // 4 block-steps of 256 float4s
    f32x4 a = __builtin_nontemporal_load(&P4[f]);
    f32x4 b = __builtin_nontemporal_load(&P4[f + 256]);
    f32x4 c = __builtin_nontemporal_load(&P4[f + 512]);
    f32x4 d = __builtin_nontemporal_load(&P4[f + 768]);
    acc += a.x * a.x + a.y * a.y + a.z * a.z + a.w * a.w;
    acc += b.x * b.x + b.y * b.y + b.z * b.z + b.w * b.w;
    acc += c.x * c.x + c.y * c.y + c.z * c.z + c.w * c.w;
    acc += d.x * d.x + d.y * d.y + d.z * d.z + d.w * d.w;
  }
  for (; f < end; f += 256) {
    f32x4 v = __builtin_nontemporal_load(&P4[f]);
    acc += v.x * v.x + v.y * v.y + v.z * v.z + v.w * v.w;
  }

  __shared__ float part[256];
  part[tid] = acc;
  __syncthreads();
  if (tid < 64) {
    // threads 4a..4a+3 all hold antenna a
    float s = (part[4 * tid] + part[4 * tid + 1]) +
              (part[4 * tid + 2] + part[4 * tid + 3]);
    partials[blockIdx.x * 64 + tid] = s;
  }
}

// ---------------------------------------------------------------------------
// Kernel 2: reduce partials[nblocks][64] -> scale[64].
// 1 block x 1024 threads: thread (j=tid>>6, a=tid&63) sums blocks b===j (mod 16)
// -> coalesced 256B wave reads, 16-way MLP. Fixed-order LDS tree over j.
// ---------------------------------------------------------------------------
__global__ __launch_bounds__(1024) void energy_finalize(
    const float* __restrict__ partials, float* __restrict__ scale, int nblocks) {
  const int tid = threadIdx.x;
  const int a = tid & 63;
  const int j = tid >> 6;  // 0..15
  float s = 0.0f;
  for (int b = j; b < nblocks; b += 16) s += partials[b * 64 + a];
  __shared__ float part[1024];
  part[tid] = s;
  __syncthreads();
  if (tid < 512) part[tid] += part[tid + 512];
  __syncthreads();
  if (tid < 256) part[tid] += part[tid + 256];
  __syncthreads();
  if (tid < 128) part[tid] += part[tid + 128];
  __syncthreads();
  if (tid < 64) {
    const float energy = part[tid] + part[tid + 64];
    scale[tid] = sqrtf(POWER_CONSTR / energy);
  }
}

// ---------------------------------------------------------------------------
// Kernel 3: out = P * scale[antenna]. Block-contiguous chunk, rolled loop
// (R7 structure — manual pipelining regressed, R8), nt load + nt store
// (R5/R7 A/B wins). Antenna fixed per thread = (tid>>2)&63.
// ---------------------------------------------------------------------------
__global__ __launch_bounds__(256) void apply_scale(
    const f32x4* __restrict__ P4, const float* __restrict__ scale,
    f32x4* __restrict__ O4, int nvec, int chunk) {
  __shared__ float s_scale[M_ANT];
  if (threadIdx.x < M_ANT) s_scale[threadIdx.x] = scale[threadIdx.x];
  __syncthreads();

  const int tid = threadIdx.x;
  const int base = blockIdx.x * chunk;
  int end = base + chunk;
  if (end > nvec) end = nvec;
  const float sc = s_scale[(tid >> 2) & 63];

  for (int f = base + tid; f < end; f += 256) {
    f32x4 v = __builtin_nontemporal_load(&P4[f]);
    v *= sc;
    __builtin_nontemporal_store(v, &O4[f]);
  }
}

extern "C" void kernel_launch(void* const* d_in, const int* in_sizes, int n_in,
                              void* d_out, int out_size, void* d_ws, size_t ws_size,
                              hipStream_t stream) {
  const f32x4* P4 = (const f32x4*)d_in[0];
  f32x4* O4 = (f32x4*)d_out;
  float* ws = (float*)d_ws;

  const int nelem = in_sizes[0];  // B * 2*M*K = 67,108,864
  const int nvec = nelem / 4;     // float4 count

  // Partial-reduction grid: 2048 blocks (8 blocks/CU), clamped to ws capacity.
  int nblocks1 = 2048;
  const size_t ws_floats = ws_size / sizeof(float);
  if (ws_floats < (size_t)nblocks1 * 64 + 64) {
    size_t cap = ws_floats > 64 ? (ws_floats - 64) / 64 : 1;
    nblocks1 = (int)(cap < 1 ? 1 : cap);
  }
  if (nblocks1 > (nvec + 255) / 256) nblocks1 = (nvec + 255) / 256;

  // Contiguous chunk per block, rounded up to 256 float4s (keeps the
  // per-thread antenna fixed and the tail clean). 2048 blocks -> 8192.
  int chunk = ((nvec + nblocks1 - 1) / nblocks1 + 255) & ~255;

  float* partials = ws;                       // nblocks1 * 64 floats
  float* scale = ws + (size_t)nblocks1 * 64;  // 64 floats

  energy_partial<<<nblocks1, 256, 0, stream>>>(P4, partials, nvec, chunk);
  energy_finalize<<<1, 1024, 0, stream>>>(partials, scale, nblocks1);

  int nblocks3 = 2048;
  int chunk3 = ((nvec + nblocks3 - 1) / nblocks3 + 255) & ~255;
  apply_scale<<<nblocks3, 256, 0, stream>>>(P4, scale, O4, nvec, chunk3);
}